// Round 15
// baseline (108.667 us; speedup 1.0000x reference)
//
#include <hip/hip_runtime.h>

#define BATCH 4
#define NPTS  8192
#define BN    (BATCH * NPTS)   // 32768
#define GRID_MAIN 1024          // 8 (b,dir) x 32 query-groups x 4 splits

typedef _Float16 f16;
typedef f16   f16x8  __attribute__((ext_vector_type(8)));
typedef float f32x16 __attribute__((ext_vector_type(16)));

// order-preserving float <-> uint for unsigned atomicMin
__device__ __forceinline__ unsigned fkey(float f) {
    unsigned u = __float_as_uint(f);
    return u ^ (unsigned)(((int)u >> 31) | 0x80000000);
}
__device__ __forceinline__ float funkey(unsigned k) {
    unsigned u = k ^ ((k & 0x80000000u) ? 0x80000000u : 0xFFFFFFFFu);
    return __uint_as_float(u);
}

// ---- pack+init: point -> f16x8 {-2x,-2y,-2z, csq_hi, csq_lo, 0,0,0} -------
// Also initializes keys (one word per thread), zero page, done counter.
// grid: (BN/256, 2) x 256
__global__ void pack_kernel(const float* __restrict__ preds,
                            const float* __restrict__ gts,
                            f16x8* __restrict__ cP,
                            f16x8* __restrict__ cG,
                            unsigned* __restrict__ keys,
                            f16x8* __restrict__ zp,
                            unsigned* __restrict__ done) {
    const int i     = blockIdx.x * 256 + threadIdx.x;
    const int which = blockIdx.y;

    keys[(size_t)which * BN + i] = 0xFFFFFFFFu;   // +inf key

    if (which == 0 && i == 0) {
        f16x8 z;
#pragma unroll
        for (int j = 0; j < 8; ++j) z[j] = (f16)0.0f;
        zp[0] = z; zp[1] = z;
        *done = 0u;
    }

    const float* src = which ? gts : preds;
    f16x8* dst       = which ? cG : cP;
    float x = src[3 * i], y = src[3 * i + 1], z = src[3 * i + 2];
    f16 xh = (f16)x, yh = (f16)y, zh = (f16)z;
    float xf = (float)xh, yf = (float)yh, zf = (float)zh;
    float csq = xf * xf + yf * yf + zf * zf;
    f16 ch = (f16)csq;
    f16 cl = (f16)(csq - (float)ch);
    f16x8 v;
    v[0] = xh * (f16)(-2.0f);
    v[1] = yh * (f16)(-2.0f);
    v[2] = zh * (f16)(-2.0f);
    v[3] = ch;
    v[4] = cl;
    v[5] = (f16)0.0f; v[6] = (f16)0.0f; v[7] = (f16)0.0f;
    dst[i] = v;
}

// ---- main: A=candidates (streamed), B=2 fixed query frags -----------------
// R14 body + candidate-tile REUSE: each loaded tile feeds 2 MFMAs (bq0,bq1)
// -> half the loads per MFMA, 2 independent chains under one load latency.
// d-tiles stay transient (consumed into scalar m0/m1), so liveness ~75 regs.
// qsq folded into the key; LAST BLOCK sums all keys (fused finalize, R9).
// grid: 1024 x 256. Wave: 64 queries (2 B-frags) x 2048 candidates, 64 iters.
// v_mfma_f32_32x32x16_f16: A 32x16 (lane: row=l&31, k=8*(l>>5)+j),
// B 16x32 (lane: col=l&31, k=8*(l>>5)+j), D: col=l&31, row=(r&3)+8*(r>>2)+4*(l>>5).
__global__ void __launch_bounds__(256, 4)
chamfer_mfma_kernel(const f16x8* __restrict__ cP,
                    const f16x8* __restrict__ cG,
                    const f16x8* __restrict__ zp,
                    unsigned* __restrict__ keys,
                    unsigned* __restrict__ done,
                    float* __restrict__ out) {
    __shared__ unsigned lastf;
    __shared__ float red[4];

    const int lane   = threadIdx.x & 63;
    const int wavein = threadIdx.x >> 6;

    const int s   = blockIdx.x & 3;              // candidate split 0..3
    const int qg  = (blockIdx.x >> 2) & 31;      // query group 0..31
    const int bd  = blockIdx.x >> 7;             // b*2 + dir, 0..7
    const int b   = bd >> 1;
    const int dir = bd & 1;                      // 0: q=preds,c=gts ; 1: swapped

    const f16x8* __restrict__ Q = dir ? cG : cP;
    const f16x8* __restrict__ C = dir ? cP : cG;

    const bool hi  = lane >= 32;                 // k-half 1: all-zero slots
    const int  l31 = lane & 31;

    // ---- B fragments: 2 x 32 fixed queries {qx,qy,qz,1,1,0,0,0}
    const int q0 = b * NPTS + (qg * 4 + wavein) * 64;
    f16x8 bq0, bq1;
    float qsq0, qsq1;
    {
        const f16x8* pQ0 = hi ? zp : (Q + q0 + l31);
        const f16x8* pQ1 = hi ? zp : (Q + q0 + 32 + l31);
        f16x8 qr0 = *pQ0;
        f16x8 qr1 = *pQ1;
        qsq0 = (float)qr0[3] + (float)qr0[4];
        qsq1 = (float)qr1[3] + (float)qr1[4];
        const f16 nh  = (f16)(-0.5f);            // -0.5 * (-2x) = x, exact
        const f16 one = hi ? (f16)0.0f : (f16)1.0f;
        bq0[0] = qr0[0] * nh; bq0[1] = qr0[1] * nh; bq0[2] = qr0[2] * nh;
        bq0[3] = one; bq0[4] = one;
        bq0[5] = (f16)0.0f; bq0[6] = (f16)0.0f; bq0[7] = (f16)0.0f;
        bq1[0] = qr1[0] * nh; bq1[1] = qr1[1] * nh; bq1[2] = qr1[2] * nh;
        bq1[3] = one; bq1[4] = one;
        bq1[5] = (f16)0.0f; bq1[6] = (f16)0.0f; bq1[7] = (f16)0.0f;
    }

    // ---- A stream: candidate tiles, raw pack; hi lanes pinned to zero page
    const int c0 = b * NPTS + s * 2048;
    const f16x8* pA  = hi ? zp : (C + c0 + l31);
    const long  step = hi ? 0 : 32;              // 32 candidates per iter

    f32x16 zacc;
#pragma unroll
    for (int i = 0; i < 16; ++i) zacc[i] = 0.0f;
    float m0 = 1e30f, m1 = 1e30f;

    for (int it = 0; it < 64; ++it) {            // 64 iters x 32 candidates
        f16x8 a = *pA;
        pA += step;
        // D[cand,query] = csq - 2<q,c>; one tile feeds both query frags
        f32x16 d0 = __builtin_amdgcn_mfma_f32_32x32x16_f16(a, bq0, zacc, 0, 0, 0);
        f32x16 d1 = __builtin_amdgcn_mfma_f32_32x32x16_f16(a, bq1, zacc, 0, 0, 0);
        {
            float t0 = fminf(fminf(d0[0],  d0[1]),  d0[2]);
            float t1 = fminf(fminf(d0[3],  d0[4]),  d0[5]);
            float t2 = fminf(fminf(d0[6],  d0[7]),  d0[8]);
            float t3 = fminf(fminf(d0[9],  d0[10]), d0[11]);
            float t4 = fminf(fminf(d0[12], d0[13]), d0[14]);
            float t5 = fminf(fminf(t0, t1), d0[15]);
            float t6 = fminf(fminf(t2, t3), t4);
            m0 = fminf(m0, fminf(t5, t6));
        }
        {
            float t0 = fminf(fminf(d1[0],  d1[1]),  d1[2]);
            float t1 = fminf(fminf(d1[3],  d1[4]),  d1[5]);
            float t2 = fminf(fminf(d1[6],  d1[7]),  d1[8]);
            float t3 = fminf(fminf(d1[9],  d1[10]), d1[11]);
            float t4 = fminf(fminf(d1[12], d1[13]), d1[14]);
            float t5 = fminf(fminf(t0, t1), d1[15]);
            float t6 = fminf(fminf(t2, t3), t4);
            m1 = fminf(m1, fminf(t5, t6));
        }
    }

    // ---- epilogue: merge candidate-row halves, fold qsq, one atomic each --
    m0 = fminf(m0, __shfl_xor(m0, 32, 64));
    m1 = fminf(m1, __shfl_xor(m1, 32, 64));
    if (!hi) {
        unsigned* __restrict__ kout = keys + (size_t)dir * BN;
        atomicMin(&kout[q0 + l31],      fkey(m0 + qsq0));
        atomicMin(&kout[q0 + 32 + l31], fkey(m1 + qsq1));
    }

    // ---- last-block finalize: sum all 2*BN keys ---------------------------
    __threadfence();
    __syncthreads();
    if (threadIdx.x == 0) {
        unsigned prev = atomicAdd(done, 1u);
        lastf = (prev == GRID_MAIN - 1) ? 1u : 0u;
    }
    __syncthreads();
    if (lastf) {
        __threadfence();                       // acquire: see all blocks' mins
        float s0 = 0.f, s1 = 0.f, s2 = 0.f, s3 = 0.f;
        const uint4* __restrict__ k4 = (const uint4*)keys;   // 16384 entries
        for (int i = threadIdx.x; i < 2 * BN / 4; i += 256) {
            uint4 kk = k4[i];
            s0 += funkey(kk.x); s1 += funkey(kk.y);
            s2 += funkey(kk.z); s3 += funkey(kk.w);
        }
        float val = (s0 + s1) + (s2 + s3);
#pragma unroll
        for (int off = 32; off > 0; off >>= 1)
            val += __shfl_down(val, off, 64);
        if (lane == 0) red[wavein] = val;
        __syncthreads();
        if (threadIdx.x == 0)
            out[0] = red[0] + red[1] + red[2] + red[3];
    }
}

extern "C" void kernel_launch(void* const* d_in, const int* in_sizes, int n_in,
                              void* d_out, int out_size, void* d_ws, size_t ws_size,
                              hipStream_t stream) {
    const float* preds = (const float*)d_in[0];
    const float* gts   = (const float*)d_in[1];
    float* out = (float*)d_out;

    // ws: zp 0..32 | done @128 | keys @256 (256KB) | cP (512KB) | cG (512KB)
    char* ws = (char*)d_ws;
    f16x8*    zp   = (f16x8*)ws;
    unsigned* done = (unsigned*)(ws + 128);
    unsigned* keys = (unsigned*)(ws + 256);
    f16x8*    cP   = (f16x8*)(ws + 256 + (size_t)2 * BN * 4);
    f16x8*    cG   = cP + BN;

    dim3 gpack(BN / 256, 2);
    pack_kernel<<<gpack, 256, 0, stream>>>(preds, gts, cP, cG, keys, zp, done);

    chamfer_mfma_kernel<<<GRID_MAIN, 256, 0, stream>>>(cP, cG, zp, keys, done, out);
}

// Round 16
// 33.532 us; speedup vs baseline: 3.2407x; 3.2407x over previous
//
#include <hip/hip_runtime.h>

#define BATCH 4
#define NPTS  8192
#define BN    (BATCH * NPTS)   // 32768

typedef _Float16 f16;
typedef f16   f16x8  __attribute__((ext_vector_type(8)));
typedef float f32x16 __attribute__((ext_vector_type(16)));

// order-preserving float <-> uint for unsigned atomicMin
__device__ __forceinline__ unsigned fkey(float f) {
    unsigned u = __float_as_uint(f);
    return u ^ (unsigned)(((int)u >> 31) | 0x80000000);
}
__device__ __forceinline__ float funkey(unsigned k) {
    unsigned u = k ^ ((k & 0x80000000u) ? 0x80000000u : 0xFFFFFFFFu);
    return __uint_as_float(u);
}

// ---- pack+init: point -> f16x8 {-2x,-2y,-2z, csq_hi, csq_lo, 0,0,0} -------
// Also initializes keys (one word per thread), the zero page, and out.
// grid: (BN/256, 2) x 256
__global__ void pack_kernel(const float* __restrict__ preds,
                            const float* __restrict__ gts,
                            f16x8* __restrict__ cP,
                            f16x8* __restrict__ cG,
                            unsigned* __restrict__ keys,
                            f16x8* __restrict__ zp,
                            float* __restrict__ out) {
    const int i     = blockIdx.x * 256 + threadIdx.x;
    const int which = blockIdx.y;

    keys[(size_t)which * BN + i] = 0xFFFFFFFFu;   // +inf key

    if (which == 0 && i == 0) {
        *out = 0.0f;
        f16x8 z;
#pragma unroll
        for (int j = 0; j < 8; ++j) z[j] = (f16)0.0f;
        zp[0] = z; zp[1] = z;
    }

    const float* src = which ? gts : preds;
    f16x8* dst       = which ? cG : cP;
    float x = src[3 * i], y = src[3 * i + 1], z = src[3 * i + 2];
    f16 xh = (f16)x, yh = (f16)y, zh = (f16)z;
    float xf = (float)xh, yf = (float)yh, zf = (float)zh;
    float csq = xf * xf + yf * yf + zf * zf;
    f16 ch = (f16)csq;
    f16 cl = (f16)(csq - (float)ch);
    f16x8 v;
    v[0] = xh * (f16)(-2.0f);
    v[1] = yh * (f16)(-2.0f);
    v[2] = zh * (f16)(-2.0f);
    v[3] = ch;
    v[4] = cl;
    v[5] = (f16)0.0f; v[6] = (f16)0.0f; v[7] = (f16)0.0f;
    dst[i] = v;
}

// ---- main: A=candidates (streamed), B=2 fixed query frags -----------------
// R14 body + candidate-tile REUSE (R15's loop, validated correct): each
// loaded tile feeds 2 MFMAs -> half the loads/MFMA, 2 independent chains
// under one load latency. d-tiles transient -> scalar m0/m1 (VGPR ~40, R15).
// SEPARATE finalize kernel: fused last-block tail costs ~75us (R9/R10/R15
// all ~104us with 3 different bodies; R8/R11/R14 fast without it).
// grid: 2048 x 256 (8 blocks/CU). Wave: 64 queries x 1024 candidates, 32 iters.
// v_mfma_f32_32x32x16_f16: A 32x16 (lane: row=l&31, k=8*(l>>5)+j),
// B 16x32 (lane: col=l&31, k=8*(l>>5)+j), D: col=l&31, row=(r&3)+8*(r>>2)+4*(l>>5).
__global__ void __launch_bounds__(256, 4)
chamfer_mfma_kernel(const f16x8* __restrict__ cP,
                    const f16x8* __restrict__ cG,
                    const f16x8* __restrict__ zp,
                    unsigned* __restrict__ keys) {
    const int lane   = threadIdx.x & 63;
    const int wavein = threadIdx.x >> 6;

    const int s   = blockIdx.x & 7;              // candidate split 0..7
    const int qg  = (blockIdx.x >> 3) & 31;      // query group 0..31
    const int bd  = blockIdx.x >> 8;             // b*2 + dir, 0..7
    const int b   = bd >> 1;
    const int dir = bd & 1;                      // 0: q=preds,c=gts ; 1: swapped

    const f16x8* __restrict__ Q = dir ? cG : cP;
    const f16x8* __restrict__ C = dir ? cP : cG;

    const bool hi  = lane >= 32;                 // k-half 1: all-zero slots
    const int  l31 = lane & 31;

    // ---- B fragments: 2 x 32 fixed queries {qx,qy,qz,1,1,0,0,0}
    const int q0 = b * NPTS + (qg * 4 + wavein) * 64;
    f16x8 bq0, bq1;
    float qsq0, qsq1;
    {
        const f16x8* pQ0 = hi ? zp : (Q + q0 + l31);
        const f16x8* pQ1 = hi ? zp : (Q + q0 + 32 + l31);
        f16x8 qr0 = *pQ0;
        f16x8 qr1 = *pQ1;
        qsq0 = (float)qr0[3] + (float)qr0[4];
        qsq1 = (float)qr1[3] + (float)qr1[4];
        const f16 nh  = (f16)(-0.5f);            // -0.5 * (-2x) = x, exact
        const f16 one = hi ? (f16)0.0f : (f16)1.0f;
        bq0[0] = qr0[0] * nh; bq0[1] = qr0[1] * nh; bq0[2] = qr0[2] * nh;
        bq0[3] = one; bq0[4] = one;
        bq0[5] = (f16)0.0f; bq0[6] = (f16)0.0f; bq0[7] = (f16)0.0f;
        bq1[0] = qr1[0] * nh; bq1[1] = qr1[1] * nh; bq1[2] = qr1[2] * nh;
        bq1[3] = one; bq1[4] = one;
        bq1[5] = (f16)0.0f; bq1[6] = (f16)0.0f; bq1[7] = (f16)0.0f;
    }

    // ---- A stream: candidate tiles, raw pack; hi lanes pinned to zero page
    const int c0 = b * NPTS + s * 1024;
    const f16x8* pA  = hi ? zp : (C + c0 + l31);
    const long  step = hi ? 0 : 32;              // 32 candidates per iter

    f32x16 zacc;
#pragma unroll
    for (int i = 0; i < 16; ++i) zacc[i] = 0.0f;
    float m0 = 1e30f, m1 = 1e30f;

    for (int it = 0; it < 32; ++it) {            // 32 iters x 32 candidates
        f16x8 a = *pA;
        pA += step;
        // D[cand,query] = csq - 2<q,c>; one tile feeds both query frags
        f32x16 d0 = __builtin_amdgcn_mfma_f32_32x32x16_f16(a, bq0, zacc, 0, 0, 0);
        f32x16 d1 = __builtin_amdgcn_mfma_f32_32x32x16_f16(a, bq1, zacc, 0, 0, 0);
        {
            float t0 = fminf(fminf(d0[0],  d0[1]),  d0[2]);
            float t1 = fminf(fminf(d0[3],  d0[4]),  d0[5]);
            float t2 = fminf(fminf(d0[6],  d0[7]),  d0[8]);
            float t3 = fminf(fminf(d0[9],  d0[10]), d0[11]);
            float t4 = fminf(fminf(d0[12], d0[13]), d0[14]);
            float t5 = fminf(fminf(t0, t1), d0[15]);
            float t6 = fminf(fminf(t2, t3), t4);
            m0 = fminf(m0, fminf(t5, t6));
        }
        {
            float t0 = fminf(fminf(d1[0],  d1[1]),  d1[2]);
            float t1 = fminf(fminf(d1[3],  d1[4]),  d1[5]);
            float t2 = fminf(fminf(d1[6],  d1[7]),  d1[8]);
            float t3 = fminf(fminf(d1[9],  d1[10]), d1[11]);
            float t4 = fminf(fminf(d1[12], d1[13]), d1[14]);
            float t5 = fminf(fminf(t0, t1), d1[15]);
            float t6 = fminf(fminf(t2, t3), t4);
            m1 = fminf(m1, fminf(t5, t6));
        }
    }

    // ---- epilogue: merge candidate-row halves, fold qsq, one atomic each --
    m0 = fminf(m0, __shfl_xor(m0, 32, 64));
    m1 = fminf(m1, __shfl_xor(m1, 32, 64));
    if (!hi) {
        unsigned* __restrict__ kout = keys + (size_t)dir * BN;
        atomicMin(&kout[q0 + l31],      fkey(m0 + qsq0));
        atomicMin(&kout[q0 + 32 + l31], fkey(m1 + qsq1));
    }
}

// ---- finalize: decode key (qsq already folded in), global sum -------------
// grid: 2*BN/256 = 256 blocks
__global__ void __launch_bounds__(256)
finalize_kernel(const unsigned* __restrict__ keys, float* __restrict__ out) {
    __shared__ float red[4];
    const int idx = blockIdx.x * 256 + threadIdx.x;   // [0, 2*BN)

    float val = funkey(keys[idx]);

#pragma unroll
    for (int off = 32; off > 0; off >>= 1)
        val += __shfl_down(val, off, 64);

    const int wave = threadIdx.x >> 6;
    const int lane = threadIdx.x & 63;
    if (lane == 0) red[wave] = val;
    __syncthreads();
    if (threadIdx.x == 0)
        atomicAdd(out, red[0] + red[1] + red[2] + red[3]);
}

extern "C" void kernel_launch(void* const* d_in, const int* in_sizes, int n_in,
                              void* d_out, int out_size, void* d_ws, size_t ws_size,
                              hipStream_t stream) {
    const float* preds = (const float*)d_in[0];
    const float* gts   = (const float*)d_in[1];
    float* out = (float*)d_out;

    // ws layout: zeropage 256B | keys 256KB | cPackP 512KB | cPackG 512KB
    char* ws = (char*)d_ws;
    f16x8*    zp   = (f16x8*)ws;
    unsigned* keys = (unsigned*)(ws + 256);
    f16x8*    cP   = (f16x8*)(ws + 256 + (size_t)2 * BN * 4);
    f16x8*    cG   = cP + BN;

    dim3 gpack(BN / 256, 2);
    pack_kernel<<<gpack, 256, 0, stream>>>(preds, gts, cP, cG, keys, zp, out);

    chamfer_mfma_kernel<<<2048, 256, 0, stream>>>(cP, cG, zp, keys);

    finalize_kernel<<<2 * BN / 256, 256, 0, stream>>>(keys, out);
}

// Round 17
// 32.033 us; speedup vs baseline: 3.3923x; 1.0468x over previous
//
#include <hip/hip_runtime.h>

#define BATCH 4
#define NPTS  8192
#define BN    (BATCH * NPTS)   // 32768

typedef _Float16 f16;
typedef f16   f16x8  __attribute__((ext_vector_type(8)));
typedef float f32x16 __attribute__((ext_vector_type(16)));

// order-preserving float <-> uint for unsigned atomicMin
__device__ __forceinline__ unsigned fkey(float f) {
    unsigned u = __float_as_uint(f);
    return u ^ (unsigned)(((int)u >> 31) | 0x80000000);
}
__device__ __forceinline__ float funkey(unsigned k) {
    unsigned u = k ^ ((k & 0x80000000u) ? 0x80000000u : 0xFFFFFFFFu);
    return __uint_as_float(u);
}

// min of 16 f32 via v_min3 tree
__device__ __forceinline__ float min16(const f32x16& d) {
    float t0 = fminf(fminf(d[0],  d[1]),  d[2]);
    float t1 = fminf(fminf(d[3],  d[4]),  d[5]);
    float t2 = fminf(fminf(d[6],  d[7]),  d[8]);
    float t3 = fminf(fminf(d[9],  d[10]), d[11]);
    float t4 = fminf(fminf(d[12], d[13]), d[14]);
    float t5 = fminf(fminf(t0, t1), d[15]);
    float t6 = fminf(fminf(t2, t3), t4);
    return fminf(t5, t6);
}

// ---- pack+init: point -> f16x8 {-2x,-2y,-2z, csq_hi, csq_lo, 0,0,0} -------
// Also initializes keys (one word per thread), the zero page, and out.
// grid: (BN/256, 2) x 256
__global__ void pack_kernel(const float* __restrict__ preds,
                            const float* __restrict__ gts,
                            f16x8* __restrict__ cP,
                            f16x8* __restrict__ cG,
                            unsigned* __restrict__ keys,
                            f16x8* __restrict__ zp,
                            float* __restrict__ out) {
    const int i     = blockIdx.x * 256 + threadIdx.x;
    const int which = blockIdx.y;

    keys[(size_t)which * BN + i] = 0xFFFFFFFFu;   // +inf key

    if (which == 0 && i == 0) {
        *out = 0.0f;
        f16x8 z;
#pragma unroll
        for (int j = 0; j < 8; ++j) z[j] = (f16)0.0f;
        zp[0] = z; zp[1] = z;
    }

    const float* src = which ? gts : preds;
    f16x8* dst       = which ? cG : cP;
    float x = src[3 * i], y = src[3 * i + 1], z = src[3 * i + 2];
    f16 xh = (f16)x, yh = (f16)y, zh = (f16)z;
    float xf = (float)xh, yf = (float)yh, zf = (float)zh;
    float csq = xf * xf + yf * yf + zf * zf;
    f16 ch = (f16)csq;
    f16 cl = (f16)(csq - (float)ch);
    f16x8 v;
    v[0] = xh * (f16)(-2.0f);
    v[1] = yh * (f16)(-2.0f);
    v[2] = zh * (f16)(-2.0f);
    v[3] = ch;
    v[4] = cl;
    v[5] = (f16)0.0f; v[6] = (f16)0.0f; v[7] = (f16)0.0f;
    dst[i] = v;
}

// ---- main: A=candidates (streamed), B=4 fixed query frags -----------------
// R16 + deeper candidate-tile reuse: each loaded tile feeds 4 MFMAs, so the
// fixed per-iteration stall (~150cy: load issue + MFMA-result wait + loop)
// amortizes over 128 matrix cycles instead of 64. d-tiles stay transient ->
// scalar m0..m3 min state (no f32x16 liveness trap: R15/R16 VGPR=40).
// grid: 2048 x 256 (8 blocks/CU, 32 waves/CU = max occupancy).
// Wave: 128 queries (4 B-frags) x 512 candidates, 16 iters, 64 MFMA.
// v_mfma_f32_32x32x16_f16: A 32x16 (lane: row=l&31, k=8*(l>>5)+j),
// B 16x32 (lane: col=l&31, k=8*(l>>5)+j), D: col=l&31, row=(r&3)+8*(r>>2)+4*(l>>5).
__global__ void __launch_bounds__(256, 4)
chamfer_mfma_kernel(const f16x8* __restrict__ cP,
                    const f16x8* __restrict__ cG,
                    const f16x8* __restrict__ zp,
                    unsigned* __restrict__ keys) {
    const int lane   = threadIdx.x & 63;
    const int wavein = threadIdx.x >> 6;

    const int s   = blockIdx.x & 15;             // candidate split 0..15
    const int qg  = (blockIdx.x >> 4) & 15;      // query group 0..15
    const int bd  = blockIdx.x >> 8;             // b*2 + dir, 0..7
    const int b   = bd >> 1;
    const int dir = bd & 1;                      // 0: q=preds,c=gts ; 1: swapped

    const f16x8* __restrict__ Q = dir ? cG : cP;
    const f16x8* __restrict__ C = dir ? cP : cG;

    const bool hi  = lane >= 32;                 // k-half 1: all-zero slots
    const int  l31 = lane & 31;

    // ---- B fragments: 4 x 32 fixed queries {qx,qy,qz,1,1,0,0,0}
    const int q0 = b * NPTS + qg * 512 + wavein * 128;
    f16x8 bq0, bq1, bq2, bq3;
    float qsq0, qsq1, qsq2, qsq3;
    {
        f16x8 qr0 = *(hi ? zp : (Q + q0 + l31));
        f16x8 qr1 = *(hi ? zp : (Q + q0 + 32 + l31));
        f16x8 qr2 = *(hi ? zp : (Q + q0 + 64 + l31));
        f16x8 qr3 = *(hi ? zp : (Q + q0 + 96 + l31));
        qsq0 = (float)qr0[3] + (float)qr0[4];
        qsq1 = (float)qr1[3] + (float)qr1[4];
        qsq2 = (float)qr2[3] + (float)qr2[4];
        qsq3 = (float)qr3[3] + (float)qr3[4];
        const f16 nh  = (f16)(-0.5f);            // -0.5 * (-2x) = x, exact
        const f16 one = hi ? (f16)0.0f : (f16)1.0f;
        const f16 zz  = (f16)0.0f;
        bq0[0] = qr0[0] * nh; bq0[1] = qr0[1] * nh; bq0[2] = qr0[2] * nh;
        bq0[3] = one; bq0[4] = one; bq0[5] = zz; bq0[6] = zz; bq0[7] = zz;
        bq1[0] = qr1[0] * nh; bq1[1] = qr1[1] * nh; bq1[2] = qr1[2] * nh;
        bq1[3] = one; bq1[4] = one; bq1[5] = zz; bq1[6] = zz; bq1[7] = zz;
        bq2[0] = qr2[0] * nh; bq2[1] = qr2[1] * nh; bq2[2] = qr2[2] * nh;
        bq2[3] = one; bq2[4] = one; bq2[5] = zz; bq2[6] = zz; bq2[7] = zz;
        bq3[0] = qr3[0] * nh; bq3[1] = qr3[1] * nh; bq3[2] = qr3[2] * nh;
        bq3[3] = one; bq3[4] = one; bq3[5] = zz; bq3[6] = zz; bq3[7] = zz;
    }

    // ---- A stream: candidate tiles, raw pack; hi lanes pinned to zero page
    const int c0 = b * NPTS + s * 512;
    const f16x8* pA  = hi ? zp : (C + c0 + l31);
    const long  step = hi ? 0 : 32;              // 32 candidates per iter

    f32x16 zacc;
#pragma unroll
    for (int i = 0; i < 16; ++i) zacc[i] = 0.0f;
    float m0 = 1e30f, m1 = 1e30f, m2 = 1e30f, m3 = 1e30f;

    for (int it = 0; it < 16; ++it) {            // 16 iters x 32 candidates
        f16x8 a = *pA;
        pA += step;
        // D[cand,query] = csq - 2<q,c>; one tile feeds all 4 query frags.
        // Interleave MFMA issue with consumption of the previous d-tile so
        // at most ~2 d-tiles are live at once.
        f32x16 d0 = __builtin_amdgcn_mfma_f32_32x32x16_f16(a, bq0, zacc, 0, 0, 0);
        f32x16 d1 = __builtin_amdgcn_mfma_f32_32x32x16_f16(a, bq1, zacc, 0, 0, 0);
        m0 = fminf(m0, min16(d0));
        f32x16 d2 = __builtin_amdgcn_mfma_f32_32x32x16_f16(a, bq2, zacc, 0, 0, 0);
        m1 = fminf(m1, min16(d1));
        f32x16 d3 = __builtin_amdgcn_mfma_f32_32x32x16_f16(a, bq3, zacc, 0, 0, 0);
        m2 = fminf(m2, min16(d2));
        m3 = fminf(m3, min16(d3));
    }

    // ---- epilogue: merge candidate-row halves, fold qsq, one atomic each --
    m0 = fminf(m0, __shfl_xor(m0, 32, 64));
    m1 = fminf(m1, __shfl_xor(m1, 32, 64));
    m2 = fminf(m2, __shfl_xor(m2, 32, 64));
    m3 = fminf(m3, __shfl_xor(m3, 32, 64));
    if (!hi) {
        unsigned* __restrict__ kout = keys + (size_t)dir * BN;
        atomicMin(&kout[q0 + l31],      fkey(m0 + qsq0));
        atomicMin(&kout[q0 + 32 + l31], fkey(m1 + qsq1));
        atomicMin(&kout[q0 + 64 + l31], fkey(m2 + qsq2));
        atomicMin(&kout[q0 + 96 + l31], fkey(m3 + qsq3));
    }
}

// ---- finalize: decode key (qsq already folded in), global sum -------------
// grid: 2*BN/256 = 256 blocks
__global__ void __launch_bounds__(256)
finalize_kernel(const unsigned* __restrict__ keys, float* __restrict__ out) {
    __shared__ float red[4];
    const int idx = blockIdx.x * 256 + threadIdx.x;   // [0, 2*BN)

    float val = funkey(keys[idx]);

#pragma unroll
    for (int off = 32; off > 0; off >>= 1)
        val += __shfl_down(val, off, 64);

    const int wave = threadIdx.x >> 6;
    const int lane = threadIdx.x & 63;
    if (lane == 0) red[wave] = val;
    __syncthreads();
    if (threadIdx.x == 0)
        atomicAdd(out, red[0] + red[1] + red[2] + red[3]);
}

extern "C" void kernel_launch(void* const* d_in, const int* in_sizes, int n_in,
                              void* d_out, int out_size, void* d_ws, size_t ws_size,
                              hipStream_t stream) {
    const float* preds = (const float*)d_in[0];
    const float* gts   = (const float*)d_in[1];
    float* out = (float*)d_out;

    // ws layout: zeropage 256B | keys 256KB | cPackP 512KB | cPackG 512KB
    char* ws = (char*)d_ws;
    f16x8*    zp   = (f16x8*)ws;
    unsigned* keys = (unsigned*)(ws + 256);
    f16x8*    cP   = (f16x8*)(ws + 256 + (size_t)2 * BN * 4);
    f16x8*    cG   = cP + BN;

    dim3 gpack(BN / 256, 2);
    pack_kernel<<<gpack, 256, 0, stream>>>(preds, gts, cP, cG, keys, zp, out);

    chamfer_mfma_kernel<<<2048, 256, 0, stream>>>(cP, cG, zp, keys);

    finalize_kernel<<<2 * BN / 256, 256, 0, stream>>>(keys, out);
}